// Round 12
// baseline (518.860 us; speedup 1.0000x reference)
//
#include <hip/hip_runtime.h>
#include <hip/hip_bf16.h>
#include <math.h>

// GATv2 3-layer GNN, MI355X. CSR-by-dst + fused online-softmax aggregation.
// R9: bf16 xl (layers 1-2). R10: defer-max. R11: parallel scan (kept); 2-deep
//     gathers regressed (occupancy > per-wave ILP) -> reverted to 1-deep.
// R12: head-split fused kernels: 8 edge-slots x 8 lanes per wave. Each
//      ~70-inst wave-iteration now covers 8 edges (was 4) -> VALU/edge halved.

__device__ __forceinline__ float lrelu(float x) { return x > 0.f ? x : 0.2f * x; }
__device__ __forceinline__ float elu1(float x) { return x > 0.f ? x : expm1f(x); }

__device__ __forceinline__ unsigned f2ord(float x) {
    unsigned b = __float_as_uint(x);
    return (b & 0x80000000u) ? ~b : (b | 0x80000000u);
}
__device__ __forceinline__ float ord2f(unsigned u) {
    unsigned b = (u & 0x80000000u) ? (u & 0x7FFFFFFFu) : ~u;
    return __uint_as_float(b);
}
__device__ __forceinline__ unsigned short f2bf(float f) {   // RNE
    unsigned u = __float_as_uint(f);
    unsigned r = u + 0x7FFFu + ((u >> 16) & 1u);
    return (unsigned short)(r >> 16);
}

// ---------------- CSR build ----------------
__global__ void k_zero_i32(int* __restrict__ p, int n) {
    int i = blockIdx.x * blockDim.x + threadIdx.x;
    if (i < n) p[i] = 0;
}

__global__ void k_hist(const int* __restrict__ ei, int E, int N, int* __restrict__ deg) {
    int e = blockIdx.x * blockDim.x + threadIdx.x;
    int Etot = E + N;
    if (e >= Etot) return;
    int d = (e < E) ? ei[E + e] : (e - E);
    atomicAdd(&deg[d], 1);
}

// parallel scan stage 1: per-block (1024 elems) exclusive prefix + block total
__global__ void __launch_bounds__(1024) k_scan_blk(
        const int* __restrict__ deg, int n,
        int* __restrict__ part, int* __restrict__ bsum) {
    __shared__ int wsum[16];
    int tid = threadIdx.x;
    int lane = tid & 63, w = tid >> 6;
    int i = blockIdx.x * 1024 + tid;
    int v = (i < n) ? deg[i] : 0;
    int s = v;
    #pragma unroll
    for (int d = 1; d < 64; d <<= 1) {
        int t = __shfl_up(s, d, 64);
        if (lane >= d) s += t;
    }
    if (lane == 63) wsum[w] = s;
    __syncthreads();
    int wbase = 0;
    for (int k = 0; k < w; k++) wbase += wsum[k];
    if (i < n) part[i] = wbase + (s - v);
    if (tid == 1023) bsum[blockIdx.x] = wbase + s;
}

// stage 2: single wave scans block totals
__global__ void k_scan_top(const int* __restrict__ bsum, int nb,
                           int* __restrict__ boff, int* __restrict__ row_off, int n) {
    int lane = threadIdx.x;   // 64 threads
    int base = 0;
    for (int st = 0; st < nb; st += 64) {
        int i = st + lane;
        int v = (i < nb) ? bsum[i] : 0;
        int s = v;
        #pragma unroll
        for (int d = 1; d < 64; d <<= 1) {
            int t = __shfl_up(s, d, 64);
            if (lane >= d) s += t;
        }
        if (i < nb) boff[i] = base + (s - v);
        base += __shfl(s, 63, 64);
    }
    if (lane == 0) row_off[n] = base;
}

// stage 3: row_off/cursor = part + block offset
__global__ void __launch_bounds__(1024) k_scan_add(
        const int* __restrict__ part, const int* __restrict__ boff, int n,
        int* __restrict__ row_off, int* __restrict__ cursor) {
    int i = blockIdx.x * 1024 + threadIdx.x;
    if (i < n) {
        int r = part[i] + boff[blockIdx.x];
        row_off[i] = r;
        cursor[i] = r;
    }
}

__global__ void k_scatter(const int* __restrict__ ei, int E, int N,
                          int* __restrict__ cursor,
                          int* __restrict__ csr_src) {
    int e = blockIdx.x * blockDim.x + threadIdx.x;
    int Etot = E + N;
    if (e >= Etot) return;
    int s, d;
    if (e < E) { s = ei[e]; d = ei[E + e]; } else { s = e - E; d = e - E; }
    int p = atomicAdd(&cursor[d], 1);
    csr_src[p] = s;
}

// ---- dual linear variant (layers 1-2, MH=128): xl written bf16, xr fp32 -----
template <int K>
__global__ void k_linear2b(const float* __restrict__ x, int N,
                           const float* __restrict__ Wl, const float* __restrict__ bl,
                           const float* __restrict__ Wr, const float* __restrict__ br,
                           unsigned short* __restrict__ xlb, float* __restrict__ xr) {
    constexpr int MH = 128, NCG = 64;
    __shared__ float xs[32 * K];
    int tid = threadIdx.x;
    int node0 = blockIdx.x * 32;
    for (int idx = tid * 4; idx < 32 * K; idx += NCG * 4 * 4) {
        int node = node0 + idx / K;
        float4 v = make_float4(0.f, 0.f, 0.f, 0.f);
        if (node < N) v = *(const float4*)(x + (size_t)node0 * K + idx);
        *(float4*)(xs + idx) = v;
    }
    __syncthreads();

    int cg = tid % NCG;
    int ng = tid / NCG;
    bool rightSide = cg >= (MH / 4);
    int c = (rightSide ? cg - MH / 4 : cg) * 4;
    const float* W  = rightSide ? Wr : Wl;
    const float* bb = rightSide ? br : bl;

    float acc[8][4];
    #pragma unroll
    for (int i = 0; i < 8; i++)
        #pragma unroll
        for (int j = 0; j < 4; j++) acc[i][j] = 0.f;

    const float* xrow = xs + ng * 8 * K;
    for (int k0 = 0; k0 < K; k0 += 4) {
        float4 wv[4];
        #pragma unroll
        for (int kk = 0; kk < 4; kk++)
            wv[kk] = *(const float4*)(W + (size_t)(k0 + kk) * MH + c);
        #pragma unroll
        for (int i = 0; i < 8; i++) {
            float4 xv = *(const float4*)(xrow + i * K + k0);
            float xvk[4] = {xv.x, xv.y, xv.z, xv.w};
            #pragma unroll
            for (int kk = 0; kk < 4; kk++) {
                acc[i][0] += xvk[kk] * wv[kk].x;
                acc[i][1] += xvk[kk] * wv[kk].y;
                acc[i][2] += xvk[kk] * wv[kk].z;
                acc[i][3] += xvk[kk] * wv[kk].w;
            }
        }
    }
    float4 bv = *(const float4*)(bb + c);
    #pragma unroll
    for (int i = 0; i < 8; i++) {
        int node = node0 + ng * 8 + i;
        if (node >= N) continue;
        float o0 = acc[i][0] + bv.x, o1 = acc[i][1] + bv.y;
        float o2 = acc[i][2] + bv.z, o3 = acc[i][3] + bv.w;
        if (rightSide) {
            *(float4*)(xr + (size_t)node * MH + c) = make_float4(o0, o1, o2, o3);
        } else {
            ushort4 ub = make_ushort4(f2bf(o0), f2bf(o1), f2bf(o2), f2bf(o3));
            *(ushort4*)(xlb + (size_t)node * MH + c) = ub;
        }
    }
}

// ---------------- layer-3 linear (128->32), 256-thread blocks ----------------
__global__ void __launch_bounds__(256) k_linear3(
        const float* __restrict__ x, int N,
        const float* __restrict__ Wl, const float* __restrict__ bl,
        const float* __restrict__ Wr, const float* __restrict__ br,
        float* __restrict__ xl, float* __restrict__ xr) {
    __shared__ float xs[32 * 128];
    int tid = threadIdx.x;
    int node0 = blockIdx.x * 32;
    for (int idx = tid * 4; idx < 32 * 128; idx += 256 * 4) {
        int node = node0 + idx / 128;
        float4 v = make_float4(0.f, 0.f, 0.f, 0.f);
        if (node < N) v = *(const float4*)(x + (size_t)node0 * 128 + idx);
        *(float4*)(xs + idx) = v;
    }
    __syncthreads();
    int cg = tid & 15, ng = tid >> 4;
    bool rightSide = cg >= 8;
    int c = (rightSide ? cg - 8 : cg) * 4;
    const float* W  = rightSide ? Wr : Wl;
    const float* bb = rightSide ? br : bl;
    float* out      = rightSide ? xr : xl;

    float acc[2][4];
    #pragma unroll
    for (int i = 0; i < 2; i++)
        #pragma unroll
        for (int j = 0; j < 4; j++) acc[i][j] = 0.f;

    const float* xrow = xs + ng * 2 * 128;
    for (int k0 = 0; k0 < 128; k0 += 4) {
        float4 wv[4];
        #pragma unroll
        for (int kk = 0; kk < 4; kk++)
            wv[kk] = *(const float4*)(W + (size_t)(k0 + kk) * 32 + c);
        #pragma unroll
        for (int i = 0; i < 2; i++) {
            float4 xv = *(const float4*)(xrow + i * 128 + k0);
            float xvk[4] = {xv.x, xv.y, xv.z, xv.w};
            #pragma unroll
            for (int kk = 0; kk < 4; kk++) {
                acc[i][0] += xvk[kk] * wv[kk].x;
                acc[i][1] += xvk[kk] * wv[kk].y;
                acc[i][2] += xvk[kk] * wv[kk].z;
                acc[i][3] += xvk[kk] * wv[kk].w;
            }
        }
    }
    float4 bv = *(const float4*)(bb + c);
    #pragma unroll
    for (int i = 0; i < 2; i++) {
        int node = node0 + ng * 2 + i;
        if (node < N) {
            float4 o = make_float4(acc[i][0] + bv.x, acc[i][1] + bv.y,
                                   acc[i][2] + bv.z, acc[i][3] + bv.w);
            *(float4*)(out + (size_t)node * 32 + c) = o;
        }
    }
}

// ---------------- fused attn+agg, bf16 xl, head-split (layers 1-2) ----------
// wave = (node, head); 8 edge-slots x 8 lanes; lane owns 8 cols of the head.
__device__ __forceinline__ void unpack8(int4 rv, float* v) {
    unsigned u0 = (unsigned)rv.x, u1 = (unsigned)rv.y;
    unsigned u2 = (unsigned)rv.z, u3 = (unsigned)rv.w;
    v[0] = __uint_as_float(u0 << 16); v[1] = __uint_as_float(u0 & 0xFFFF0000u);
    v[2] = __uint_as_float(u1 << 16); v[3] = __uint_as_float(u1 & 0xFFFF0000u);
    v[4] = __uint_as_float(u2 << 16); v[5] = __uint_as_float(u2 & 0xFFFF0000u);
    v[6] = __uint_as_float(u3 << 16); v[7] = __uint_as_float(u3 & 0xFFFF0000u);
}

__global__ void __launch_bounds__(256) k_fusedb(
        const int* __restrict__ row_off, const int* __restrict__ csr_src,
        const unsigned short* __restrict__ xlb, const float* __restrict__ xr,
        const float* __restrict__ att, const float* __restrict__ bias,
        float* __restrict__ hout, int N) {
    constexpr int HC = 128, CPL = 8;
    int gw = (blockIdx.x * blockDim.x + threadIdx.x) >> 6;   // wave id
    int node = gw >> 1, head = gw & 1;
    int lane = threadIdx.x & 63;
    if (node >= N) return;
    int slot = lane >> 3;        // 0..7
    int j = lane & 7;            // lane within slot
    int c0 = head * 64 + j * CPL;

    int p0 = row_off[node], p1 = row_off[node + 1];

    float xrv[CPL], attv[CPL];
    {
        float4 a = *(const float4*)(xr + (size_t)node * HC + c0);
        float4 b = *(const float4*)(xr + (size_t)node * HC + c0 + 4);
        xrv[0] = a.x; xrv[1] = a.y; xrv[2] = a.z; xrv[3] = a.w;
        xrv[4] = b.x; xrv[5] = b.y; xrv[6] = b.z; xrv[7] = b.w;
        float4 c = *(const float4*)(att + c0);
        float4 d = *(const float4*)(att + c0 + 4);
        attv[0] = c.x; attv[1] = c.y; attv[2] = c.z; attv[3] = c.w;
        attv[4] = d.x; attv[5] = d.y; attv[6] = d.z; attv[7] = d.w;
    }

    float m = -INFINITY, den = 0.f;
    float acc[CPL];
    #pragma unroll
    for (int q = 0; q < CPL; q++) acc[q] = 0.f;

    int p = p0 + slot;
    int s = (p < p1) ? csr_src[p] : 0;
    while (p < p1) {
        int pn = p + 8;
        int sn = (pn < p1) ? csr_src[pn] : 0;   // prefetch next index
        int4 rv = *(const int4*)(xlb + (size_t)s * HC + c0);  // head half-row
        float xlv[CPL];
        unpack8(rv, xlv);
        float part = 0.f;
        #pragma unroll
        for (int q = 0; q < CPL; q++) {
            float t = xlv[q] + xrv[q];
            part = fmaf(fmaxf(t, 0.2f * t), attv[q], part);
        }
        part += __shfl_xor(part, 1, 64);
        part += __shfl_xor(part, 2, 64);
        part += __shfl_xor(part, 4, 64);   // reduce over 8 lanes of slot
        // defer-max: rescale only on big new max (exp bounded by e^8)
        if (part > m + 8.f) {
            float corr = __expf(m - part);   // m=-inf -> 0
            den *= corr;
            #pragma unroll
            for (int q = 0; q < CPL; q++) acc[q] *= corr;
            m = part;
        }
        float ex = __expf(part - m);
        den += ex;
        #pragma unroll
        for (int q = 0; q < CPL; q++) acc[q] = fmaf(ex, xlv[q], acc[q]);
        p = pn; s = sn;
    }
    // combine the 8 slots (flash-style rescale)
    float mAll = fmaxf(m, __shfl_xor(m, 8, 64));
    mAll = fmaxf(mAll, __shfl_xor(mAll, 16, 64));
    mAll = fmaxf(mAll, __shfl_xor(mAll, 32, 64));
    float scale = __expf(m - mAll);      // empty slot -> 0
    float dtot = den * scale;
    dtot += __shfl_xor(dtot, 8, 64);
    dtot += __shfl_xor(dtot, 16, 64);
    dtot += __shfl_xor(dtot, 32, 64);
    #pragma unroll
    for (int q = 0; q < CPL; q++) {
        float a = acc[q] * scale;
        a += __shfl_xor(a, 8, 64);
        a += __shfl_xor(a, 16, 64);
        a += __shfl_xor(a, 32, 64);
        acc[q] = a;
    }
    if (slot == 0) {
        float inv = 1.0f / (dtot + 1e-16f);
        #pragma unroll
        for (int q = 0; q < CPL; q++) {
            float v = acc[q] * inv + bias[c0 + q];
            hout[(size_t)node * HC + c0 + q] = elu1(v);
        }
    }
}

// ---------------- fused attn+agg, fp32 (layer 3, HC=32, H=1) ----------------
// wave per node; 8 edge-slots x 8 lanes; lane owns 4 cols (float4 gathers).
__global__ void __launch_bounds__(256) k_fused3(
        const int* __restrict__ row_off, const int* __restrict__ csr_src,
        const float* __restrict__ xl, const float* __restrict__ xr,
        const float* __restrict__ att, const float* __restrict__ bias,
        float* __restrict__ hout, int N) {
    constexpr int HC = 32, CPL = 4;
    int node = (blockIdx.x * blockDim.x + threadIdx.x) >> 6;
    int lane = threadIdx.x & 63;
    if (node >= N) return;
    int slot = lane >> 3;
    int j = lane & 7;
    int c0 = j * CPL;

    int p0 = row_off[node], p1 = row_off[node + 1];

    float4 xrq = *(const float4*)(xr + (size_t)node * HC + c0);
    float4 atq = *(const float4*)(att + c0);
    float xrv[CPL] = {xrq.x, xrq.y, xrq.z, xrq.w};
    float attv[CPL] = {atq.x, atq.y, atq.z, atq.w};

    float m = -INFINITY, den = 0.f;
    float acc[CPL];
    #pragma unroll
    for (int q = 0; q < CPL; q++) acc[q] = 0.f;

    int p = p0 + slot;
    int s = (p < p1) ? csr_src[p] : 0;
    while (p < p1) {
        int pn = p + 8;
        int sn = (pn < p1) ? csr_src[pn] : 0;
        float4 xq = *(const float4*)(xl + (size_t)s * HC + c0);
        float xlv[CPL] = {xq.x, xq.y, xq.z, xq.w};
        float part = 0.f;
        #pragma unroll
        for (int q = 0; q < CPL; q++) {
            float t = xlv[q] + xrv[q];
            part = fmaf(fmaxf(t, 0.2f * t), attv[q], part);
        }
        part += __shfl_xor(part, 1, 64);
        part += __shfl_xor(part, 2, 64);
        part += __shfl_xor(part, 4, 64);
        if (part > m + 8.f) {
            float corr = __expf(m - part);
            den *= corr;
            #pragma unroll
            for (int q = 0; q < CPL; q++) acc[q] *= corr;
            m = part;
        }
        float ex = __expf(part - m);
        den += ex;
        #pragma unroll
        for (int q = 0; q < CPL; q++) acc[q] = fmaf(ex, xlv[q], acc[q]);
        p = pn; s = sn;
    }
    float mAll = fmaxf(m, __shfl_xor(m, 8, 64));
    mAll = fmaxf(mAll, __shfl_xor(mAll, 16, 64));
    mAll = fmaxf(mAll, __shfl_xor(mAll, 32, 64));
    float scale = __expf(m - mAll);
    float dtot = den * scale;
    dtot += __shfl_xor(dtot, 8, 64);
    dtot += __shfl_xor(dtot, 16, 64);
    dtot += __shfl_xor(dtot, 32, 64);
    #pragma unroll
    for (int q = 0; q < CPL; q++) {
        float a = acc[q] * scale;
        a += __shfl_xor(a, 8, 64);
        a += __shfl_xor(a, 16, 64);
        a += __shfl_xor(a, 32, 64);
        acc[q] = a;
    }
    if (slot == 0) {
        float inv = 1.0f / (dtot + 1e-16f);
        #pragma unroll
        for (int q = 0; q < CPL; q++) {
            float v = acc[q] * inv + bias[c0 + q];
            hout[(size_t)node * HC + c0 + q] = elu1(v);
        }
    }
}

// ---------------- graph pooling (parallel, 2-stage) ----------------
__global__ void __launch_bounds__(256) k_pool_partial(
        const float* __restrict__ h, const int* __restrict__ batch, int N, int G,
        float* __restrict__ gsum, unsigned* __restrict__ gmax) {
    __shared__ float lsum[512];
    __shared__ unsigned lmax[512];
    int tid = threadIdx.x;
    for (int i = tid; i < G * 32; i += 256) { lsum[i] = 0.f; lmax[i] = 0u; }
    __syncthreads();
    int chunk = (N + gridDim.x - 1) / gridDim.x;
    int start = blockIdx.x * chunk;
    int end = min(N, start + chunk);
    int col = tid & 31, row = tid >> 5;
    int gc = -1; float ps = 0.f; unsigned pm = 0u;
    for (int i = start + row; i < end; i += 8) {
        int g = batch[i];
        if (g != gc) {
            if (gc >= 0) { atomicAdd(&lsum[gc * 32 + col], ps); atomicMax(&lmax[gc * 32 + col], pm); }
            gc = g; ps = 0.f; pm = 0u;
        }
        float v = h[(size_t)i * 32 + col];
        ps += v; pm = max(pm, f2ord(v));
    }
    if (gc >= 0) { atomicAdd(&lsum[gc * 32 + col], ps); atomicMax(&lmax[gc * 32 + col], pm); }
    __syncthreads();
    for (int i = tid; i < G * 32; i += 256) {
        if (lmax[i]) {
            atomicAdd(&gsum[i], lsum[i]);
            atomicMax(&gmax[i], lmax[i]);
        }
    }
}

__global__ void k_pool_final(const float* __restrict__ gsum, const unsigned* __restrict__ gmax,
                             const int* __restrict__ batch, int N, float* __restrict__ out) {
    int g = blockIdx.x;
    int t = threadIdx.x;
    __shared__ int s_cnt;
    if (t == 0) {
        int lo = 0, hi = N;
        while (lo < hi) { int m = (lo + hi) >> 1; if (batch[m] < g) lo = m + 1; else hi = m; }
        int a = lo;
        lo = a; hi = N;
        while (lo < hi) { int m = (lo + hi) >> 1; if (batch[m] < g + 1) lo = m + 1; else hi = m; }
        s_cnt = lo - a;
    }
    __syncthreads();
    if (t < 32) {
        out[g * 64 + t] = gsum[g * 32 + t] / (float)max(s_cnt, 1);
    } else {
        out[g * 64 + t] = ord2f(gmax[g * 32 + (t - 32)]);
    }
}

extern "C" void kernel_launch(void* const* d_in, const int* in_sizes, int n_in,
                              void* d_out, int out_size, void* d_ws, size_t ws_size,
                              hipStream_t stream) {
    const float* x      = (const float*)d_in[0];
    const int*   ei     = (const int*)d_in[1];
    const int*   batch  = (const int*)d_in[2];
    const float* Wl1 = (const float*)d_in[3],  *bl1 = (const float*)d_in[4];
    const float* Wr1 = (const float*)d_in[5],  *br1 = (const float*)d_in[6];
    const float* att1= (const float*)d_in[7],  *b1  = (const float*)d_in[8];
    const float* Wl2 = (const float*)d_in[9],  *bl2 = (const float*)d_in[10];
    const float* Wr2 = (const float*)d_in[11], *br2 = (const float*)d_in[12];
    const float* att2= (const float*)d_in[13], *b2  = (const float*)d_in[14];
    const float* Wl3 = (const float*)d_in[15], *bl3 = (const float*)d_in[16];
    const float* Wr3 = (const float*)d_in[17], *br3 = (const float*)d_in[18];
    const float* att3= (const float*)d_in[19], *b3  = (const float*)d_in[20];

    int N = in_sizes[0] / 8;
    int E = in_sizes[1] / 2;
    int G = out_size / 64;
    int Etot = E + N;
    int nb = (N + 1023) / 1024;   // scan blocks

    char* w = (char*)d_ws;
    auto carve = [&](size_t bytes) {
        void* p = (void*)w;
        w += (bytes + 255) & ~(size_t)255;
        return p;
    };
    int*            deg     = (int*)carve((size_t)N * 4);
    int*            row_off = (int*)carve((size_t)(N + 1) * 4);
    int*            cursor  = (int*)carve((size_t)N * 4);
    int*            part    = (int*)carve((size_t)N * 4);
    int*            bsum    = (int*)carve((size_t)nb * 4);
    int*            boff    = (int*)carve((size_t)nb * 4);
    int*            csr_src = (int*)carve((size_t)Etot * 4);
    float*          gsum    = (float*)carve((size_t)G * 32 * 4);
    unsigned*       gmax    = (unsigned*)carve((size_t)G * 32 * 4);
    unsigned short* xlb     = (unsigned short*)carve((size_t)N * 128 * 2);  // bf16 xl
    float*          bufA    = (float*)carve((size_t)N * 128 * 4);  // fp32 xl (layer 3)
    float*          bufB    = (float*)carve((size_t)N * 128 * 4);  // xr
    float*          bufC    = (float*)carve((size_t)N * 128 * 4);  // h (layer outputs)
    (void)ws_size; (void)n_in;

    // ---- CSR by dst (incl. self loops) + pool accumulator init ----
    k_zero_i32<<<(N + 255) / 256, 256, 0, stream>>>(deg, N);
    k_zero_i32<<<(2 * G * 32 + 255) / 256, 256, 0, stream>>>((int*)gsum, 2 * G * 32);
    k_hist<<<(Etot + 255) / 256, 256, 0, stream>>>(ei, E, N, deg);
    k_scan_blk<<<nb, 1024, 0, stream>>>(deg, N, part, bsum);
    k_scan_top<<<1, 64, 0, stream>>>(bsum, nb, boff, row_off, N);
    k_scan_add<<<nb, 1024, 0, stream>>>(part, boff, N, row_off, cursor);
    k_scatter<<<(Etot + 255) / 256, 256, 0, stream>>>(ei, E, N, cursor, csr_src);

    int grdLin = (N + 31) / 32;
    int grdFused  = (N + 3) / 4;              // 1 wave per node
    int grdFusedH = (2 * N + 3) / 4;          // 1 wave per (node, head)

    // ---- Layer 1: K=8 -> 128 (H=2,C=64), bf16 xl ----
    k_linear2b<8><<<grdLin, 256, 0, stream>>>(x, N, Wl1, bl1, Wr1, br1, xlb, bufB);
    k_fusedb<<<grdFusedH, 256, 0, stream>>>(row_off, csr_src, xlb, bufB, att1, b1, bufC, N);

    // ---- Layer 2: 128 -> 128, bf16 xl ----
    k_linear2b<128><<<grdLin, 256, 0, stream>>>(bufC, N, Wl2, bl2, Wr2, br2, xlb, bufB);
    k_fusedb<<<grdFusedH, 256, 0, stream>>>(row_off, csr_src, xlb, bufB, att2, b2, bufC, N);

    // ---- Layer 3: 128 -> 32 (H=1,C=32), all fp32 ----
    k_linear3<<<grdLin, 256, 0, stream>>>(bufC, N, Wl3, bl3, Wr3, br3, bufA, bufB);
    k_fused3<<<grdFused, 256, 0, stream>>>(row_off, csr_src, bufA, bufB, att3, b3, bufC, N);

    // ---- pooling ----
    k_pool_partial<<<256, 256, 0, stream>>>(bufC, batch, N, G, gsum, gmax);
    k_pool_final<<<G, 64, 0, stream>>>(gsum, gmax, batch, N, (float*)d_out);
}

// Round 13
// 475.109 us; speedup vs baseline: 1.0921x; 1.0921x over previous
//
#include <hip/hip_runtime.h>
#include <hip/hip_bf16.h>
#include <math.h>

// GATv2 3-layer GNN, MI355X. CSR-by-dst + fused online-softmax aggregation.
// Proven config ledger:
//   fusedb (layers 1-2): R10 body = 4 slots x 16 lanes, 1-deep gather, bf16 xl,
//     defer-max, 36 VGPR -> 71us measured. (2-deep=76us R11, head-split=100us R12.)
//   fused3 (layer 3): 8 slots x 8 lanes, float4 full-row gathers (R12, keep).
//   parallel 3-stage scan (R11, keep). 256-thr lin3 (R10, keep).
// R13: revert fusedb to R10 body; merge zero-init launches.

__device__ __forceinline__ float lrelu(float x) { return x > 0.f ? x : 0.2f * x; }
__device__ __forceinline__ float elu1(float x) { return x > 0.f ? x : expm1f(x); }

__device__ __forceinline__ unsigned f2ord(float x) {
    unsigned b = __float_as_uint(x);
    return (b & 0x80000000u) ? ~b : (b | 0x80000000u);
}
__device__ __forceinline__ float ord2f(unsigned u) {
    unsigned b = (u & 0x80000000u) ? (u & 0x7FFFFFFFu) : ~u;
    return __uint_as_float(b);
}
__device__ __forceinline__ unsigned short f2bf(float f) {   // RNE
    unsigned u = __float_as_uint(f);
    unsigned r = u + 0x7FFFu + ((u >> 16) & 1u);
    return (unsigned short)(r >> 16);
}

// ---------------- init: deg=0, pool accumulators=0 ----------------
__global__ void k_init(int* __restrict__ deg, int N, int* __restrict__ pa, int PA) {
    int i = blockIdx.x * blockDim.x + threadIdx.x;
    int stride = gridDim.x * blockDim.x;
    for (int k = i; k < N; k += stride) deg[k] = 0;
    for (int k = i; k < PA; k += stride) pa[k] = 0;
}

__global__ void k_hist(const int* __restrict__ ei, int E, int N, int* __restrict__ deg) {
    int e = blockIdx.x * blockDim.x + threadIdx.x;
    int Etot = E + N;
    if (e >= Etot) return;
    int d = (e < E) ? ei[E + e] : (e - E);
    atomicAdd(&deg[d], 1);
}

// parallel scan stage 1: per-block (1024 elems) exclusive prefix + block total
__global__ void __launch_bounds__(1024) k_scan_blk(
        const int* __restrict__ deg, int n,
        int* __restrict__ part, int* __restrict__ bsum) {
    __shared__ int wsum[16];
    int tid = threadIdx.x;
    int lane = tid & 63, w = tid >> 6;
    int i = blockIdx.x * 1024 + tid;
    int v = (i < n) ? deg[i] : 0;
    int s = v;
    #pragma unroll
    for (int d = 1; d < 64; d <<= 1) {
        int t = __shfl_up(s, d, 64);
        if (lane >= d) s += t;
    }
    if (lane == 63) wsum[w] = s;
    __syncthreads();
    int wbase = 0;
    for (int k = 0; k < w; k++) wbase += wsum[k];
    if (i < n) part[i] = wbase + (s - v);
    if (tid == 1023) bsum[blockIdx.x] = wbase + s;
}

// stage 2: single wave scans block totals
__global__ void k_scan_top(const int* __restrict__ bsum, int nb,
                           int* __restrict__ boff, int* __restrict__ row_off, int n) {
    int lane = threadIdx.x;   // 64 threads
    int base = 0;
    for (int st = 0; st < nb; st += 64) {
        int i = st + lane;
        int v = (i < nb) ? bsum[i] : 0;
        int s = v;
        #pragma unroll
        for (int d = 1; d < 64; d <<= 1) {
            int t = __shfl_up(s, d, 64);
            if (lane >= d) s += t;
        }
        if (i < nb) boff[i] = base + (s - v);
        base += __shfl(s, 63, 64);
    }
    if (lane == 0) row_off[n] = base;
}

// stage 3: row_off/cursor = part + block offset
__global__ void __launch_bounds__(1024) k_scan_add(
        const int* __restrict__ part, const int* __restrict__ boff, int n,
        int* __restrict__ row_off, int* __restrict__ cursor) {
    int i = blockIdx.x * 1024 + threadIdx.x;
    if (i < n) {
        int r = part[i] + boff[blockIdx.x];
        row_off[i] = r;
        cursor[i] = r;
    }
}

__global__ void k_scatter(const int* __restrict__ ei, int E, int N,
                          int* __restrict__ cursor,
                          int* __restrict__ csr_src) {
    int e = blockIdx.x * blockDim.x + threadIdx.x;
    int Etot = E + N;
    if (e >= Etot) return;
    int s, d;
    if (e < E) { s = ei[e]; d = ei[E + e]; } else { s = e - E; d = e - E; }
    int p = atomicAdd(&cursor[d], 1);
    csr_src[p] = s;
}

// ---- dual linear variant (layers 1-2, MH=128): xl written bf16, xr fp32 -----
template <int K>
__global__ void k_linear2b(const float* __restrict__ x, int N,
                           const float* __restrict__ Wl, const float* __restrict__ bl,
                           const float* __restrict__ Wr, const float* __restrict__ br,
                           unsigned short* __restrict__ xlb, float* __restrict__ xr) {
    constexpr int MH = 128, NCG = 64;
    __shared__ float xs[32 * K];
    int tid = threadIdx.x;
    int node0 = blockIdx.x * 32;
    for (int idx = tid * 4; idx < 32 * K; idx += NCG * 4 * 4) {
        int node = node0 + idx / K;
        float4 v = make_float4(0.f, 0.f, 0.f, 0.f);
        if (node < N) v = *(const float4*)(x + (size_t)node0 * K + idx);
        *(float4*)(xs + idx) = v;
    }
    __syncthreads();

    int cg = tid % NCG;
    int ng = tid / NCG;
    bool rightSide = cg >= (MH / 4);
    int c = (rightSide ? cg - MH / 4 : cg) * 4;
    const float* W  = rightSide ? Wr : Wl;
    const float* bb = rightSide ? br : bl;

    float acc[8][4];
    #pragma unroll
    for (int i = 0; i < 8; i++)
        #pragma unroll
        for (int j = 0; j < 4; j++) acc[i][j] = 0.f;

    const float* xrow = xs + ng * 8 * K;
    for (int k0 = 0; k0 < K; k0 += 4) {
        float4 wv[4];
        #pragma unroll
        for (int kk = 0; kk < 4; kk++)
            wv[kk] = *(const float4*)(W + (size_t)(k0 + kk) * MH + c);
        #pragma unroll
        for (int i = 0; i < 8; i++) {
            float4 xv = *(const float4*)(xrow + i * K + k0);
            float xvk[4] = {xv.x, xv.y, xv.z, xv.w};
            #pragma unroll
            for (int kk = 0; kk < 4; kk++) {
                acc[i][0] += xvk[kk] * wv[kk].x;
                acc[i][1] += xvk[kk] * wv[kk].y;
                acc[i][2] += xvk[kk] * wv[kk].z;
                acc[i][3] += xvk[kk] * wv[kk].w;
            }
        }
    }
    float4 bv = *(const float4*)(bb + c);
    #pragma unroll
    for (int i = 0; i < 8; i++) {
        int node = node0 + ng * 8 + i;
        if (node >= N) continue;
        float o0 = acc[i][0] + bv.x, o1 = acc[i][1] + bv.y;
        float o2 = acc[i][2] + bv.z, o3 = acc[i][3] + bv.w;
        if (rightSide) {
            *(float4*)(xr + (size_t)node * MH + c) = make_float4(o0, o1, o2, o3);
        } else {
            ushort4 ub = make_ushort4(f2bf(o0), f2bf(o1), f2bf(o2), f2bf(o3));
            *(ushort4*)(xlb + (size_t)node * MH + c) = ub;
        }
    }
}

// ---------------- layer-3 linear (128->32), 256-thread blocks ----------------
__global__ void __launch_bounds__(256) k_linear3(
        const float* __restrict__ x, int N,
        const float* __restrict__ Wl, const float* __restrict__ bl,
        const float* __restrict__ Wr, const float* __restrict__ br,
        float* __restrict__ xl, float* __restrict__ xr) {
    __shared__ float xs[32 * 128];
    int tid = threadIdx.x;
    int node0 = blockIdx.x * 32;
    for (int idx = tid * 4; idx < 32 * 128; idx += 256 * 4) {
        int node = node0 + idx / 128;
        float4 v = make_float4(0.f, 0.f, 0.f, 0.f);
        if (node < N) v = *(const float4*)(x + (size_t)node0 * 128 + idx);
        *(float4*)(xs + idx) = v;
    }
    __syncthreads();
    int cg = tid & 15, ng = tid >> 4;
    bool rightSide = cg >= 8;
    int c = (rightSide ? cg - 8 : cg) * 4;
    const float* W  = rightSide ? Wr : Wl;
    const float* bb = rightSide ? br : bl;
    float* out      = rightSide ? xr : xl;

    float acc[2][4];
    #pragma unroll
    for (int i = 0; i < 2; i++)
        #pragma unroll
        for (int j = 0; j < 4; j++) acc[i][j] = 0.f;

    const float* xrow = xs + ng * 2 * 128;
    for (int k0 = 0; k0 < 128; k0 += 4) {
        float4 wv[4];
        #pragma unroll
        for (int kk = 0; kk < 4; kk++)
            wv[kk] = *(const float4*)(W + (size_t)(k0 + kk) * 32 + c);
        #pragma unroll
        for (int i = 0; i < 2; i++) {
            float4 xv = *(const float4*)(xrow + i * 128 + k0);
            float xvk[4] = {xv.x, xv.y, xv.z, xv.w};
            #pragma unroll
            for (int kk = 0; kk < 4; kk++) {
                acc[i][0] += xvk[kk] * wv[kk].x;
                acc[i][1] += xvk[kk] * wv[kk].y;
                acc[i][2] += xvk[kk] * wv[kk].z;
                acc[i][3] += xvk[kk] * wv[kk].w;
            }
        }
    }
    float4 bv = *(const float4*)(bb + c);
    #pragma unroll
    for (int i = 0; i < 2; i++) {
        int node = node0 + ng * 2 + i;
        if (node < N) {
            float4 o = make_float4(acc[i][0] + bv.x, acc[i][1] + bv.y,
                                   acc[i][2] + bv.z, acc[i][3] + bv.w);
            *(float4*)(out + (size_t)node * 32 + c) = o;
        }
    }
}

// ---------------- fused attn+agg, bf16 xl (layers 1-2, HC=128) --------------
// R10 measured-best body: 4 slots x 16 lanes, 1-deep gather, defer-max.
__device__ __forceinline__ void unpack8(int4 rv, float* v) {
    unsigned u0 = (unsigned)rv.x, u1 = (unsigned)rv.y;
    unsigned u2 = (unsigned)rv.z, u3 = (unsigned)rv.w;
    v[0] = __uint_as_float(u0 << 16); v[1] = __uint_as_float(u0 & 0xFFFF0000u);
    v[2] = __uint_as_float(u1 << 16); v[3] = __uint_as_float(u1 & 0xFFFF0000u);
    v[4] = __uint_as_float(u2 << 16); v[5] = __uint_as_float(u2 & 0xFFFF0000u);
    v[6] = __uint_as_float(u3 << 16); v[7] = __uint_as_float(u3 & 0xFFFF0000u);
}

__global__ void k_fusedb(const int* __restrict__ row_off, const int* __restrict__ csr_src,
                         const unsigned short* __restrict__ xlb, const float* __restrict__ xr,
                         const float* __restrict__ att, const float* __restrict__ bias,
                         float* __restrict__ hout, int N) {
    constexpr int HC = 128, CPL = 8, GROUP = 8;  // C=64: 8 lanes/head
    int wid = (blockIdx.x * blockDim.x + threadIdx.x) >> 6;
    int lane = threadIdx.x & 63;
    if (wid >= N) return;
    int slot = lane >> 4;
    int j = lane & 15;
    int c0 = j * CPL;

    int p0 = row_off[wid], p1 = row_off[wid + 1];

    float xrv[CPL], attv[CPL];
    {
        float4 a = *(const float4*)(xr + (size_t)wid * HC + c0);
        float4 b = *(const float4*)(xr + (size_t)wid * HC + c0 + 4);
        xrv[0] = a.x; xrv[1] = a.y; xrv[2] = a.z; xrv[3] = a.w;
        xrv[4] = b.x; xrv[5] = b.y; xrv[6] = b.z; xrv[7] = b.w;
        float4 c = *(const float4*)(att + c0);
        float4 d = *(const float4*)(att + c0 + 4);
        attv[0] = c.x; attv[1] = c.y; attv[2] = c.z; attv[3] = c.w;
        attv[4] = d.x; attv[5] = d.y; attv[6] = d.z; attv[7] = d.w;
    }

    float m = -INFINITY, den = 0.f;
    float acc[CPL];
    #pragma unroll
    for (int q = 0; q < CPL; q++) acc[q] = 0.f;

    int p = p0 + slot;
    int s = (p < p1) ? csr_src[p] : 0;
    while (p < p1) {
        int pn = p + 4;
        int sn = (pn < p1) ? csr_src[pn] : 0;
        int4 rv = *(const int4*)(xlb + (size_t)s * HC + c0);   // 8 bf16 in 16B
        float xlv[CPL];
        unpack8(rv, xlv);
        float part = 0.f;
        #pragma unroll
        for (int q = 0; q < CPL; q++) {
            float t = xlv[q] + xrv[q];
            part = fmaf(fmaxf(t, 0.2f * t), attv[q], part);
        }
        #pragma unroll
        for (int msk = 1; msk < GROUP; msk <<= 1) part += __shfl_xor(part, msk, 64);
        // defer-max: rescale only on big new max (exp(part-m) <= e^8 bounded)
        if (part > m + 8.f) {
            float corr = __expf(m - part);   // m=-inf -> 0 (zeroes empty state)
            den *= corr;
            #pragma unroll
            for (int q = 0; q < CPL; q++) acc[q] *= corr;
            m = part;
        }
        float ex = __expf(part - m);
        den += ex;
        #pragma unroll
        for (int q = 0; q < CPL; q++) acc[q] = fmaf(ex, xlv[q], acc[q]);
        p = pn; s = sn;
    }
    float mAll = fmaxf(m, __shfl_xor(m, 16, 64));
    mAll = fmaxf(mAll, __shfl_xor(mAll, 32, 64));
    float scale = __expf(m - mAll);
    float dtot = den * scale;
    dtot += __shfl_xor(dtot, 16, 64);
    dtot += __shfl_xor(dtot, 32, 64);
    #pragma unroll
    for (int q = 0; q < CPL; q++) {
        float a = acc[q] * scale;
        a += __shfl_xor(a, 16, 64);
        a += __shfl_xor(a, 32, 64);
        acc[q] = a;
    }
    if (slot == 0) {
        float inv = 1.0f / (dtot + 1e-16f);
        #pragma unroll
        for (int q = 0; q < CPL; q++) {
            float v = acc[q] * inv + bias[c0 + q];
            hout[(size_t)wid * HC + c0 + q] = elu1(v);
        }
    }
}

// ---------------- fused attn+agg, fp32 (layer 3, HC=32, H=1) ----------------
// 8 edge-slots x 8 lanes; lane owns 4 cols (float4 full-row gathers), 8 edges/iter.
__global__ void __launch_bounds__(256) k_fused3(
        const int* __restrict__ row_off, const int* __restrict__ csr_src,
        const float* __restrict__ xl, const float* __restrict__ xr,
        const float* __restrict__ att, const float* __restrict__ bias,
        float* __restrict__ hout, int N) {
    constexpr int HC = 32, CPL = 4;
    int node = (blockIdx.x * blockDim.x + threadIdx.x) >> 6;
    int lane = threadIdx.x & 63;
    if (node >= N) return;
    int slot = lane >> 3;
    int j = lane & 7;
    int c0 = j * CPL;

    int p0 = row_off[node], p1 = row_off[node + 1];

    float4 xrq = *(const float4*)(xr + (size_t)node * HC + c0);
    float4 atq = *(const float4*)(att + c0);
    float xrv[CPL] = {xrq.x, xrq.y, xrq.z, xrq.w};
    float attv[CPL] = {atq.x, atq.y, atq.z, atq.w};

    float m = -INFINITY, den = 0.f;
    float acc[CPL];
    #pragma unroll
    for (int q = 0; q < CPL; q++) acc[q] = 0.f;

    int p = p0 + slot;
    int s = (p < p1) ? csr_src[p] : 0;
    while (p < p1) {
        int pn = p + 8;
        int sn = (pn < p1) ? csr_src[pn] : 0;
        float4 xq = *(const float4*)(xl + (size_t)s * HC + c0);
        float xlv[CPL] = {xq.x, xq.y, xq.z, xq.w};
        float part = 0.f;
        #pragma unroll
        for (int q = 0; q < CPL; q++) {
            float t = xlv[q] + xrv[q];
            part = fmaf(fmaxf(t, 0.2f * t), attv[q], part);
        }
        part += __shfl_xor(part, 1, 64);
        part += __shfl_xor(part, 2, 64);
        part += __shfl_xor(part, 4, 64);
        if (part > m + 8.f) {
            float corr = __expf(m - part);
            den *= corr;
            #pragma unroll
            for (int q = 0; q < CPL; q++) acc[q] *= corr;
            m = part;
        }
        float ex = __expf(part - m);
        den += ex;
        #pragma unroll
        for (int q = 0; q < CPL; q++) acc[q] = fmaf(ex, xlv[q], acc[q]);
        p = pn; s = sn;
    }
    float mAll = fmaxf(m, __shfl_xor(m, 8, 64));
    mAll = fmaxf(mAll, __shfl_xor(mAll, 16, 64));
    mAll = fmaxf(mAll, __shfl_xor(mAll, 32, 64));
    float scale = __expf(m - mAll);
    float dtot = den * scale;
    dtot += __shfl_xor(dtot, 8, 64);
    dtot += __shfl_xor(dtot, 16, 64);
    dtot += __shfl_xor(dtot, 32, 64);
    #pragma unroll
    for (int q = 0; q < CPL; q++) {
        float a = acc[q] * scale;
        a += __shfl_xor(a, 8, 64);
        a += __shfl_xor(a, 16, 64);
        a += __shfl_xor(a, 32, 64);
        acc[q] = a;
    }
    if (slot == 0) {
        float inv = 1.0f / (dtot + 1e-16f);
        #pragma unroll
        for (int q = 0; q < CPL; q++) {
            float v = acc[q] * inv + bias[c0 + q];
            hout[(size_t)node * HC + c0 + q] = elu1(v);
        }
    }
}

// ---------------- graph pooling (parallel, 2-stage) ----------------
__global__ void __launch_bounds__(256) k_pool_partial(
        const float* __restrict__ h, const int* __restrict__ batch, int N, int G,
        float* __restrict__ gsum, unsigned* __restrict__ gmax) {
    __shared__ float lsum[512];
    __shared__ unsigned lmax[512];
    int tid = threadIdx.x;
    for (int i = tid; i < G * 32; i += 256) { lsum[i] = 0.f; lmax[i] = 0u; }
    __syncthreads();
    int chunk = (N + gridDim.x - 1) / gridDim.x;
    int start = blockIdx.x * chunk;
    int end = min(N, start + chunk);
    int col = tid & 31, row = tid >> 5;
    int gc = -1; float ps = 0.f; unsigned pm = 0u;
    for (int i = start + row; i < end; i += 8) {
        int g = batch[i];
        if (g != gc) {
            if (gc >= 0) { atomicAdd(&lsum[gc * 32 + col], ps); atomicMax(&lmax[gc * 32 + col], pm); }
            gc = g; ps = 0.f; pm = 0u;
        }
        float v = h[(size_t)i * 32 + col];
        ps += v; pm = max(pm, f2ord(v));
    }
    if (gc >= 0) { atomicAdd(&lsum[gc * 32 + col], ps); atomicMax(&lmax[gc * 32 + col], pm); }
    __syncthreads();
    for (int i = tid; i < G * 32; i += 256) {
        if (lmax[i]) {
            atomicAdd(&gsum[i], lsum[i]);
            atomicMax(&gmax[i], lmax[i]);
        }
    }
}

__global__ void k_pool_final(const float* __restrict__ gsum, const unsigned* __restrict__ gmax,
                             const int* __restrict__ batch, int N, float* __restrict__ out) {
    int g = blockIdx.x;
    int t = threadIdx.x;
    __shared__ int s_cnt;
    if (t == 0) {
        int lo = 0, hi = N;
        while (lo < hi) { int m = (lo + hi) >> 1; if (batch[m] < g) lo = m + 1; else hi = m; }
        int a = lo;
        lo = a; hi = N;
        while (lo < hi) { int m = (lo + hi) >> 1; if (batch[m] < g + 1) lo = m + 1; else hi = m; }
        s_cnt = lo - a;
    }
    __syncthreads();
    if (t < 32) {
        out[g * 64 + t] = gsum[g * 32 + t] / (float)max(s_cnt, 1);
    } else {
        out[g * 64 + t] = ord2f(gmax[g * 32 + (t - 32)]);
    }
}

extern "C" void kernel_launch(void* const* d_in, const int* in_sizes, int n_in,
                              void* d_out, int out_size, void* d_ws, size_t ws_size,
                              hipStream_t stream) {
    const float* x      = (const float*)d_in[0];
    const int*   ei     = (const int*)d_in[1];
    const int*   batch  = (const int*)d_in[2];
    const float* Wl1 = (const float*)d_in[3],  *bl1 = (const float*)d_in[4];
    const float* Wr1 = (const float*)d_in[5],  *br1 = (const float*)d_in[6];
    const float* att1= (const float*)d_in[7],  *b1  = (const float*)d_in[8];
    const float* Wl2 = (const float*)d_in[9],  *bl2 = (const float*)d_in[10];
    const float* Wr2 = (const float*)d_in[11], *br2 = (const float*)d_in[12];
    const float* att2= (const float*)d_in[13], *b2  = (const float*)d_in[14];
    const float* Wl3 = (const float*)d_in[15], *bl3 = (const float*)d_in[16];
    const float* Wr3 = (const float*)d_in[17], *br3 = (const float*)d_in[18];
    const float* att3= (const float*)d_in[19], *b3  = (const float*)d_in[20];

    int N = in_sizes[0] / 8;
    int E = in_sizes[1] / 2;
    int G = out_size / 64;
    int Etot = E + N;
    int nb = (N + 1023) / 1024;   // scan blocks

    char* w = (char*)d_ws;
    auto carve = [&](size_t bytes) {
        void* p = (void*)w;
        w += (bytes + 255) & ~(size_t)255;
        return p;
    };
    int*            deg     = (int*)carve((size_t)N * 4);
    int*            row_off = (int*)carve((size_t)(N + 1) * 4);
    int*            cursor  = (int*)carve((size_t)N * 4);
    int*            part    = (int*)carve((size_t)N * 4);
    int*            bsum    = (int*)carve((size_t)nb * 4);
    int*            boff    = (int*)carve((size_t)nb * 4);
    int*            csr_src = (int*)carve((size_t)Etot * 4);
    int*            poolacc = (int*)carve((size_t)(2 * G * 32) * 4);  // gsum|gmax
    float*          gsum    = (float*)poolacc;
    unsigned*       gmax    = (unsigned*)(poolacc + G * 32);
    unsigned short* xlb     = (unsigned short*)carve((size_t)N * 128 * 2);  // bf16 xl
    float*          bufA    = (float*)carve((size_t)N * 128 * 4);  // fp32 xl (layer 3)
    float*          bufB    = (float*)carve((size_t)N * 128 * 4);  // xr
    float*          bufC    = (float*)carve((size_t)N * 128 * 4);  // h (layer outputs)
    (void)ws_size; (void)n_in;

    // ---- init + CSR by dst (incl. self loops) ----
    k_init<<<128, 256, 0, stream>>>(deg, N, poolacc, 2 * G * 32);
    k_hist<<<(Etot + 255) / 256, 256, 0, stream>>>(ei, E, N, deg);
    k_scan_blk<<<nb, 1024, 0, stream>>>(deg, N, part, bsum);
    k_scan_top<<<1, 64, 0, stream>>>(bsum, nb, boff, row_off, N);
    k_scan_add<<<nb, 1024, 0, stream>>>(part, boff, N, row_off, cursor);
    k_scatter<<<(Etot + 255) / 256, 256, 0, stream>>>(ei, E, N, cursor, csr_src);

    int grdLin = (N + 31) / 32;
    int grdFused = (N + 3) / 4;   // 1 wave per node

    // ---- Layer 1: K=8 -> 128 (H=2,C=64), bf16 xl ----
    k_linear2b<8><<<grdLin, 256, 0, stream>>>(x, N, Wl1, bl1, Wr1, br1, xlb, bufB);
    k_fusedb<<<grdFused, 256, 0, stream>>>(row_off, csr_src, xlb, bufB, att1, b1, bufC, N);

    // ---- Layer 2: 128 -> 128, bf16 xl ----
    k_linear2b<128><<<grdLin, 256, 0, stream>>>(bufC, N, Wl2, bl2, Wr2, br2, xlb, bufB);
    k_fusedb<<<grdFused, 256, 0, stream>>>(row_off, csr_src, xlb, bufB, att2, b2, bufC, N);

    // ---- Layer 3: 128 -> 32 (H=1,C=32), all fp32 ----
    k_linear3<<<grdLin, 256, 0, stream>>>(bufC, N, Wl3, bl3, Wr3, br3, bufA, bufB);
    k_fused3<<<grdFused, 256, 0, stream>>>(row_off, csr_src, bufA, bufB, att3, b3, bufC, N);

    // ---- pooling ----
    k_pool_partial<<<256, 256, 0, stream>>>(bufC, batch, N, G, gsum, gmax);
    k_pool_final<<<G, 64, 0, stream>>>(gsum, gmax, batch, N, (float*)d_out);
}

// Round 14
// 450.536 us; speedup vs baseline: 1.1517x; 1.0545x over previous
//
#include <hip/hip_runtime.h>
#include <hip/hip_bf16.h>
#include <math.h>

// GATv2 3-layer GNN, MI355X. CSR-by-dst + fused online-softmax aggregation.
// Proven ledger: fusedb = 4slots x 16lanes, 1-deep, bf16 xl, defer-max (71us);
//   fused3 = 8slots x 8lanes full-row; parallel 3-stage scan; 256-thr lin3.
// R14: csr_src as ushort (N<65536); layer-3 xl bf16 (1 cache line/edge row);
//      32-bit gather offsets.

__device__ __forceinline__ float lrelu(float x) { return x > 0.f ? x : 0.2f * x; }
__device__ __forceinline__ float elu1(float x) { return x > 0.f ? x : expm1f(x); }

__device__ __forceinline__ unsigned f2ord(float x) {
    unsigned b = __float_as_uint(x);
    return (b & 0x80000000u) ? ~b : (b | 0x80000000u);
}
__device__ __forceinline__ float ord2f(unsigned u) {
    unsigned b = (u & 0x80000000u) ? (u & 0x7FFFFFFFu) : ~u;
    return __uint_as_float(b);
}
__device__ __forceinline__ unsigned short f2bf(float f) {   // RNE
    unsigned u = __float_as_uint(f);
    unsigned r = u + 0x7FFFu + ((u >> 16) & 1u);
    return (unsigned short)(r >> 16);
}

// ---------------- init: deg=0, pool accumulators=0 ----------------
__global__ void k_init(int* __restrict__ deg, int N, int* __restrict__ pa, int PA) {
    int i = blockIdx.x * blockDim.x + threadIdx.x;
    int stride = gridDim.x * blockDim.x;
    for (int k = i; k < N; k += stride) deg[k] = 0;
    for (int k = i; k < PA; k += stride) pa[k] = 0;
}

__global__ void k_hist(const int* __restrict__ ei, int E, int N, int* __restrict__ deg) {
    int e = blockIdx.x * blockDim.x + threadIdx.x;
    int Etot = E + N;
    if (e >= Etot) return;
    int d = (e < E) ? ei[E + e] : (e - E);
    atomicAdd(&deg[d], 1);
}

// parallel scan stage 1: per-block (1024 elems) exclusive prefix + block total
__global__ void __launch_bounds__(1024) k_scan_blk(
        const int* __restrict__ deg, int n,
        int* __restrict__ part, int* __restrict__ bsum) {
    __shared__ int wsum[16];
    int tid = threadIdx.x;
    int lane = tid & 63, w = tid >> 6;
    int i = blockIdx.x * 1024 + tid;
    int v = (i < n) ? deg[i] : 0;
    int s = v;
    #pragma unroll
    for (int d = 1; d < 64; d <<= 1) {
        int t = __shfl_up(s, d, 64);
        if (lane >= d) s += t;
    }
    if (lane == 63) wsum[w] = s;
    __syncthreads();
    int wbase = 0;
    for (int k = 0; k < w; k++) wbase += wsum[k];
    if (i < n) part[i] = wbase + (s - v);
    if (tid == 1023) bsum[blockIdx.x] = wbase + s;
}

// stage 2: single wave scans block totals
__global__ void k_scan_top(const int* __restrict__ bsum, int nb,
                           int* __restrict__ boff, int* __restrict__ row_off, int n) {
    int lane = threadIdx.x;   // 64 threads
    int base = 0;
    for (int st = 0; st < nb; st += 64) {
        int i = st + lane;
        int v = (i < nb) ? bsum[i] : 0;
        int s = v;
        #pragma unroll
        for (int d = 1; d < 64; d <<= 1) {
            int t = __shfl_up(s, d, 64);
            if (lane >= d) s += t;
        }
        if (i < nb) boff[i] = base + (s - v);
        base += __shfl(s, 63, 64);
    }
    if (lane == 0) row_off[n] = base;
}

// stage 3: row_off/cursor = part + block offset
__global__ void __launch_bounds__(1024) k_scan_add(
        const int* __restrict__ part, const int* __restrict__ boff, int n,
        int* __restrict__ row_off, int* __restrict__ cursor) {
    int i = blockIdx.x * 1024 + threadIdx.x;
    if (i < n) {
        int r = part[i] + boff[blockIdx.x];
        row_off[i] = r;
        cursor[i] = r;
    }
}

__global__ void k_scatter(const int* __restrict__ ei, int E, int N,
                          int* __restrict__ cursor,
                          unsigned short* __restrict__ csr_src) {
    int e = blockIdx.x * blockDim.x + threadIdx.x;
    int Etot = E + N;
    if (e >= Etot) return;
    int s, d;
    if (e < E) { s = ei[e]; d = ei[E + e]; } else { s = e - E; d = e - E; }
    int p = atomicAdd(&cursor[d], 1);
    csr_src[p] = (unsigned short)s;
}

// ---- dual linear variant (layers 1-2, MH=128): xl written bf16, xr fp32 -----
template <int K>
__global__ void k_linear2b(const float* __restrict__ x, int N,
                           const float* __restrict__ Wl, const float* __restrict__ bl,
                           const float* __restrict__ Wr, const float* __restrict__ br,
                           unsigned short* __restrict__ xlb, float* __restrict__ xr) {
    constexpr int MH = 128, NCG = 64;
    __shared__ float xs[32 * K];
    int tid = threadIdx.x;
    int node0 = blockIdx.x * 32;
    for (int idx = tid * 4; idx < 32 * K; idx += NCG * 4 * 4) {
        int node = node0 + idx / K;
        float4 v = make_float4(0.f, 0.f, 0.f, 0.f);
        if (node < N) v = *(const float4*)(x + (size_t)node0 * K + idx);
        *(float4*)(xs + idx) = v;
    }
    __syncthreads();

    int cg = tid % NCG;
    int ng = tid / NCG;
    bool rightSide = cg >= (MH / 4);
    int c = (rightSide ? cg - MH / 4 : cg) * 4;
    const float* W  = rightSide ? Wr : Wl;
    const float* bb = rightSide ? br : bl;

    float acc[8][4];
    #pragma unroll
    for (int i = 0; i < 8; i++)
        #pragma unroll
        for (int j = 0; j < 4; j++) acc[i][j] = 0.f;

    const float* xrow = xs + ng * 8 * K;
    for (int k0 = 0; k0 < K; k0 += 4) {
        float4 wv[4];
        #pragma unroll
        for (int kk = 0; kk < 4; kk++)
            wv[kk] = *(const float4*)(W + (size_t)(k0 + kk) * MH + c);
        #pragma unroll
        for (int i = 0; i < 8; i++) {
            float4 xv = *(const float4*)(xrow + i * K + k0);
            float xvk[4] = {xv.x, xv.y, xv.z, xv.w};
            #pragma unroll
            for (int kk = 0; kk < 4; kk++) {
                acc[i][0] += xvk[kk] * wv[kk].x;
                acc[i][1] += xvk[kk] * wv[kk].y;
                acc[i][2] += xvk[kk] * wv[kk].z;
                acc[i][3] += xvk[kk] * wv[kk].w;
            }
        }
    }
    float4 bv = *(const float4*)(bb + c);
    #pragma unroll
    for (int i = 0; i < 8; i++) {
        int node = node0 + ng * 8 + i;
        if (node >= N) continue;
        float o0 = acc[i][0] + bv.x, o1 = acc[i][1] + bv.y;
        float o2 = acc[i][2] + bv.z, o3 = acc[i][3] + bv.w;
        if (rightSide) {
            *(float4*)(xr + (size_t)node * MH + c) = make_float4(o0, o1, o2, o3);
        } else {
            ushort4 ub = make_ushort4(f2bf(o0), f2bf(o1), f2bf(o2), f2bf(o3));
            *(ushort4*)(xlb + (size_t)node * MH + c) = ub;
        }
    }
}

// ------- layer-3 linear (128->32): xl written bf16 [N,32], xr fp32 ----------
__global__ void __launch_bounds__(256) k_linear3b(
        const float* __restrict__ x, int N,
        const float* __restrict__ Wl, const float* __restrict__ bl,
        const float* __restrict__ Wr, const float* __restrict__ br,
        unsigned short* __restrict__ xlb3, float* __restrict__ xr) {
    __shared__ float xs[32 * 128];
    int tid = threadIdx.x;
    int node0 = blockIdx.x * 32;
    for (int idx = tid * 4; idx < 32 * 128; idx += 256 * 4) {
        int node = node0 + idx / 128;
        float4 v = make_float4(0.f, 0.f, 0.f, 0.f);
        if (node < N) v = *(const float4*)(x + (size_t)node0 * 128 + idx);
        *(float4*)(xs + idx) = v;
    }
    __syncthreads();
    int cg = tid & 15, ng = tid >> 4;
    bool rightSide = cg >= 8;
    int c = (rightSide ? cg - 8 : cg) * 4;
    const float* W  = rightSide ? Wr : Wl;
    const float* bb = rightSide ? br : bl;

    float acc[2][4];
    #pragma unroll
    for (int i = 0; i < 2; i++)
        #pragma unroll
        for (int j = 0; j < 4; j++) acc[i][j] = 0.f;

    const float* xrow = xs + ng * 2 * 128;
    for (int k0 = 0; k0 < 128; k0 += 4) {
        float4 wv[4];
        #pragma unroll
        for (int kk = 0; kk < 4; kk++)
            wv[kk] = *(const float4*)(W + (size_t)(k0 + kk) * 32 + c);
        #pragma unroll
        for (int i = 0; i < 2; i++) {
            float4 xv = *(const float4*)(xrow + i * 128 + k0);
            float xvk[4] = {xv.x, xv.y, xv.z, xv.w};
            #pragma unroll
            for (int kk = 0; kk < 4; kk++) {
                acc[i][0] += xvk[kk] * wv[kk].x;
                acc[i][1] += xvk[kk] * wv[kk].y;
                acc[i][2] += xvk[kk] * wv[kk].z;
                acc[i][3] += xvk[kk] * wv[kk].w;
            }
        }
    }
    float4 bv = *(const float4*)(bb + c);
    #pragma unroll
    for (int i = 0; i < 2; i++) {
        int node = node0 + ng * 2 + i;
        if (node >= N) continue;
        float o0 = acc[i][0] + bv.x, o1 = acc[i][1] + bv.y;
        float o2 = acc[i][2] + bv.z, o3 = acc[i][3] + bv.w;
        if (rightSide) {
            *(float4*)(xr + (size_t)node * 32 + c) = make_float4(o0, o1, o2, o3);
        } else {
            ushort4 ub = make_ushort4(f2bf(o0), f2bf(o1), f2bf(o2), f2bf(o3));
            *(ushort4*)(xlb3 + (size_t)node * 32 + c) = ub;
        }
    }
}

// ---------------- fused attn+agg, bf16 xl (layers 1-2, HC=128) --------------
// R10 measured-best body: 4 slots x 16 lanes, 1-deep gather, defer-max.
__device__ __forceinline__ void unpack8(int4 rv, float* v) {
    unsigned u0 = (unsigned)rv.x, u1 = (unsigned)rv.y;
    unsigned u2 = (unsigned)rv.z, u3 = (unsigned)rv.w;
    v[0] = __uint_as_float(u0 << 16); v[1] = __uint_as_float(u0 & 0xFFFF0000u);
    v[2] = __uint_as_float(u1 << 16); v[3] = __uint_as_float(u1 & 0xFFFF0000u);
    v[4] = __uint_as_float(u2 << 16); v[5] = __uint_as_float(u2 & 0xFFFF0000u);
    v[6] = __uint_as_float(u3 << 16); v[7] = __uint_as_float(u3 & 0xFFFF0000u);
}

__global__ void k_fusedb(const int* __restrict__ row_off, const unsigned short* __restrict__ csr_src,
                         const unsigned short* __restrict__ xlb, const float* __restrict__ xr,
                         const float* __restrict__ att, const float* __restrict__ bias,
                         float* __restrict__ hout, int N) {
    constexpr int HC = 128, CPL = 8, GROUP = 8;  // C=64: 8 lanes/head
    int wid = (blockIdx.x * blockDim.x + threadIdx.x) >> 6;
    int lane = threadIdx.x & 63;
    if (wid >= N) return;
    int slot = lane >> 4;
    int j = lane & 15;
    int c0 = j * CPL;

    int p0 = row_off[wid], p1 = row_off[wid + 1];

    float xrv[CPL], attv[CPL];
    {
        float4 a = *(const float4*)(xr + (size_t)wid * HC + c0);
        float4 b = *(const float4*)(xr + (size_t)wid * HC + c0 + 4);
        xrv[0] = a.x; xrv[1] = a.y; xrv[2] = a.z; xrv[3] = a.w;
        xrv[4] = b.x; xrv[5] = b.y; xrv[6] = b.z; xrv[7] = b.w;
        float4 c = *(const float4*)(att + c0);
        float4 d = *(const float4*)(att + c0 + 4);
        attv[0] = c.x; attv[1] = c.y; attv[2] = c.z; attv[3] = c.w;
        attv[4] = d.x; attv[5] = d.y; attv[6] = d.z; attv[7] = d.w;
    }

    float m = -INFINITY, den = 0.f;
    float acc[CPL];
    #pragma unroll
    for (int q = 0; q < CPL; q++) acc[q] = 0.f;

    int p = p0 + slot;
    unsigned s = (p < p1) ? (unsigned)csr_src[p] : 0u;
    while (p < p1) {
        int pn = p + 4;
        unsigned sn = (pn < p1) ? (unsigned)csr_src[pn] : 0u;
        int4 rv = *(const int4*)(xlb + (s * 128u + (unsigned)c0));  // 32-bit offset
        float xlv[CPL];
        unpack8(rv, xlv);
        float part = 0.f;
        #pragma unroll
        for (int q = 0; q < CPL; q++) {
            float t = xlv[q] + xrv[q];
            part = fmaf(fmaxf(t, 0.2f * t), attv[q], part);
        }
        #pragma unroll
        for (int msk = 1; msk < GROUP; msk <<= 1) part += __shfl_xor(part, msk, 64);
        // defer-max: rescale only on big new max (exp(part-m) <= e^8 bounded)
        if (part > m + 8.f) {
            float corr = __expf(m - part);   // m=-inf -> 0 (zeroes empty state)
            den *= corr;
            #pragma unroll
            for (int q = 0; q < CPL; q++) acc[q] *= corr;
            m = part;
        }
        float ex = __expf(part - m);
        den += ex;
        #pragma unroll
        for (int q = 0; q < CPL; q++) acc[q] = fmaf(ex, xlv[q], acc[q]);
        p = pn; s = sn;
    }
    float mAll = fmaxf(m, __shfl_xor(m, 16, 64));
    mAll = fmaxf(mAll, __shfl_xor(mAll, 32, 64));
    float scale = __expf(m - mAll);
    float dtot = den * scale;
    dtot += __shfl_xor(dtot, 16, 64);
    dtot += __shfl_xor(dtot, 32, 64);
    #pragma unroll
    for (int q = 0; q < CPL; q++) {
        float a = acc[q] * scale;
        a += __shfl_xor(a, 16, 64);
        a += __shfl_xor(a, 32, 64);
        acc[q] = a;
    }
    if (slot == 0) {
        float inv = 1.0f / (dtot + 1e-16f);
        #pragma unroll
        for (int q = 0; q < CPL; q++) {
            float v = acc[q] * inv + bias[c0 + q];
            hout[(size_t)wid * HC + c0 + q] = elu1(v);
        }
    }
}

// ---------------- fused attn+agg, bf16 xl (layer 3, HC=32, H=1) -------------
// 8 edge-slots x 8 lanes; lane owns 4 cols (8B bf16 loads -> 1 line/edge row).
__global__ void __launch_bounds__(256) k_fused3(
        const int* __restrict__ row_off, const unsigned short* __restrict__ csr_src,
        const unsigned short* __restrict__ xlb3, const float* __restrict__ xr,
        const float* __restrict__ att, const float* __restrict__ bias,
        float* __restrict__ hout, int N) {
    constexpr int HC = 32, CPL = 4;
    int node = (blockIdx.x * blockDim.x + threadIdx.x) >> 6;
    int lane = threadIdx.x & 63;
    if (node >= N) return;
    int slot = lane >> 3;
    int j = lane & 7;
    int c0 = j * CPL;

    int p0 = row_off[node], p1 = row_off[node + 1];

    float4 xrq = *(const float4*)(xr + (size_t)node * HC + c0);
    float4 atq = *(const float4*)(att + c0);
    float xrv[CPL] = {xrq.x, xrq.y, xrq.z, xrq.w};
    float attv[CPL] = {atq.x, atq.y, atq.z, atq.w};

    float m = -INFINITY, den = 0.f;
    float acc[CPL];
    #pragma unroll
    for (int q = 0; q < CPL; q++) acc[q] = 0.f;

    int p = p0 + slot;
    unsigned s = (p < p1) ? (unsigned)csr_src[p] : 0u;
    while (p < p1) {
        int pn = p + 8;
        unsigned sn = (pn < p1) ? (unsigned)csr_src[pn] : 0u;
        int2 rv = *(const int2*)(xlb3 + (s * 32u + (unsigned)c0));  // 4 bf16 in 8B
        float xlv[CPL];
        {
            unsigned u0 = (unsigned)rv.x, u1 = (unsigned)rv.y;
            xlv[0] = __uint_as_float(u0 << 16); xlv[1] = __uint_as_float(u0 & 0xFFFF0000u);
            xlv[2] = __uint_as_float(u1 << 16); xlv[3] = __uint_as_float(u1 & 0xFFFF0000u);
        }
        float part = 0.f;
        #pragma unroll
        for (int q = 0; q < CPL; q++) {
            float t = xlv[q] + xrv[q];
            part = fmaf(fmaxf(t, 0.2f * t), attv[q], part);
        }
        part += __shfl_xor(part, 1, 64);
        part += __shfl_xor(part, 2, 64);
        part += __shfl_xor(part, 4, 64);
        if (part > m + 8.f) {
            float corr = __expf(m - part);
            den *= corr;
            #pragma unroll
            for (int q = 0; q < CPL; q++) acc[q] *= corr;
            m = part;
        }
        float ex = __expf(part - m);
        den += ex;
        #pragma unroll
        for (int q = 0; q < CPL; q++) acc[q] = fmaf(ex, xlv[q], acc[q]);
        p = pn; s = sn;
    }
    float mAll = fmaxf(m, __shfl_xor(m, 8, 64));
    mAll = fmaxf(mAll, __shfl_xor(mAll, 16, 64));
    mAll = fmaxf(mAll, __shfl_xor(mAll, 32, 64));
    float scale = __expf(m - mAll);
    float dtot = den * scale;
    dtot += __shfl_xor(dtot, 8, 64);
    dtot += __shfl_xor(dtot, 16, 64);
    dtot += __shfl_xor(dtot, 32, 64);
    #pragma unroll
    for (int q = 0; q < CPL; q++) {
        float a = acc[q] * scale;
        a += __shfl_xor(a, 8, 64);
        a += __shfl_xor(a, 16, 64);
        a += __shfl_xor(a, 32, 64);
        acc[q] = a;
    }
    if (slot == 0) {
        float inv = 1.0f / (dtot + 1e-16f);
        #pragma unroll
        for (int q = 0; q < CPL; q++) {
            float v = acc[q] * inv + bias[c0 + q];
            hout[(size_t)node * HC + c0 + q] = elu1(v);
        }
    }
}

// ---------------- graph pooling (parallel, 2-stage) ----------------
__global__ void __launch_bounds__(256) k_pool_partial(
        const float* __restrict__ h, const int* __restrict__ batch, int N, int G,
        float* __restrict__ gsum, unsigned* __restrict__ gmax) {
    __shared__ float lsum[512];
    __shared__ unsigned lmax[512];
    int tid = threadIdx.x;
    for (int i = tid; i < G * 32; i += 256) { lsum[i] = 0.f; lmax[i] = 0u; }
    __syncthreads();
    int chunk = (N + gridDim.x - 1) / gridDim.x;
    int start = blockIdx.x * chunk;
    int end = min(N, start + chunk);
    int col = tid & 31, row = tid >> 5;
    int gc = -1; float ps = 0.f; unsigned pm = 0u;
    for (int i = start + row; i < end; i += 8) {
        int g = batch[i];
        if (g != gc) {
            if (gc >= 0) { atomicAdd(&lsum[gc * 32 + col], ps); atomicMax(&lmax[gc * 32 + col], pm); }
            gc = g; ps = 0.f; pm = 0u;
        }
        float v = h[(size_t)i * 32 + col];
        ps += v; pm = max(pm, f2ord(v));
    }
    if (gc >= 0) { atomicAdd(&lsum[gc * 32 + col], ps); atomicMax(&lmax[gc * 32 + col], pm); }
    __syncthreads();
    for (int i = tid; i < G * 32; i += 256) {
        if (lmax[i]) {
            atomicAdd(&gsum[i], lsum[i]);
            atomicMax(&gmax[i], lmax[i]);
        }
    }
}

__global__ void k_pool_final(const float* __restrict__ gsum, const unsigned* __restrict__ gmax,
                             const int* __restrict__ batch, int N, float* __restrict__ out) {
    int g = blockIdx.x;
    int t = threadIdx.x;
    __shared__ int s_cnt;
    if (t == 0) {
        int lo = 0, hi = N;
        while (lo < hi) { int m = (lo + hi) >> 1; if (batch[m] < g) lo = m + 1; else hi = m; }
        int a = lo;
        lo = a; hi = N;
        while (lo < hi) { int m = (lo + hi) >> 1; if (batch[m] < g + 1) lo = m + 1; else hi = m; }
        s_cnt = lo - a;
    }
    __syncthreads();
    if (t < 32) {
        out[g * 64 + t] = gsum[g * 32 + t] / (float)max(s_cnt, 1);
    } else {
        out[g * 64 + t] = ord2f(gmax[g * 32 + (t - 32)]);
    }
}

extern "C" void kernel_launch(void* const* d_in, const int* in_sizes, int n_in,
                              void* d_out, int out_size, void* d_ws, size_t ws_size,
                              hipStream_t stream) {
    const float* x      = (const float*)d_in[0];
    const int*   ei     = (const int*)d_in[1];
    const int*   batch  = (const int*)d_in[2];
    const float* Wl1 = (const float*)d_in[3],  *bl1 = (const float*)d_in[4];
    const float* Wr1 = (const float*)d_in[5],  *br1 = (const float*)d_in[6];
    const float* att1= (const float*)d_in[7],  *b1  = (const float*)d_in[8];
    const float* Wl2 = (const float*)d_in[9],  *bl2 = (const float*)d_in[10];
    const float* Wr2 = (const float*)d_in[11], *br2 = (const float*)d_in[12];
    const float* att2= (const float*)d_in[13], *b2  = (const float*)d_in[14];
    const float* Wl3 = (const float*)d_in[15], *bl3 = (const float*)d_in[16];
    const float* Wr3 = (const float*)d_in[17], *br3 = (const float*)d_in[18];
    const float* att3= (const float*)d_in[19], *b3  = (const float*)d_in[20];

    int N = in_sizes[0] / 8;
    int E = in_sizes[1] / 2;
    int G = out_size / 64;
    int Etot = E + N;
    int nb = (N + 1023) / 1024;   // scan blocks

    char* w = (char*)d_ws;
    auto carve = [&](size_t bytes) {
        void* p = (void*)w;
        w += (bytes + 255) & ~(size_t)255;
        return p;
    };
    int*            deg     = (int*)carve((size_t)N * 4);
    int*            row_off = (int*)carve((size_t)(N + 1) * 4);
    int*            cursor  = (int*)carve((size_t)N * 4);
    int*            part    = (int*)carve((size_t)N * 4);
    int*            bsum    = (int*)carve((size_t)nb * 4);
    int*            boff    = (int*)carve((size_t)nb * 4);
    unsigned short* csr_src = (unsigned short*)carve((size_t)Etot * 2);
    int*            poolacc = (int*)carve((size_t)(2 * G * 32) * 4);  // gsum|gmax
    float*          gsum    = (float*)poolacc;
    unsigned*       gmax    = (unsigned*)(poolacc + G * 32);
    unsigned short* xlb     = (unsigned short*)carve((size_t)N * 128 * 2);  // bf16 xl
    float*          bufB    = (float*)carve((size_t)N * 128 * 4);  // xr
    float*          bufC    = (float*)carve((size_t)N * 128 * 4);  // h (layer outputs)
    (void)ws_size; (void)n_in;

    // ---- init + CSR by dst (incl. self loops) ----
    k_init<<<128, 256, 0, stream>>>(deg, N, poolacc, 2 * G * 32);
    k_hist<<<(Etot + 255) / 256, 256, 0, stream>>>(ei, E, N, deg);
    k_scan_blk<<<nb, 1024, 0, stream>>>(deg, N, part, bsum);
    k_scan_top<<<1, 64, 0, stream>>>(bsum, nb, boff, row_off, N);
    k_scan_add<<<nb, 1024, 0, stream>>>(part, boff, N, row_off, cursor);
    k_scatter<<<(Etot + 255) / 256, 256, 0, stream>>>(ei, E, N, cursor, csr_src);

    int grdLin = (N + 31) / 32;
    int grdFused = (N + 3) / 4;   // 1 wave per node

    // ---- Layer 1: K=8 -> 128 (H=2,C=64), bf16 xl ----
    k_linear2b<8><<<grdLin, 256, 0, stream>>>(x, N, Wl1, bl1, Wr1, br1, xlb, bufB);
    k_fusedb<<<grdFused, 256, 0, stream>>>(row_off, csr_src, xlb, bufB, att1, b1, bufC, N);

    // ---- Layer 2: 128 -> 128, bf16 xl ----
    k_linear2b<128><<<grdLin, 256, 0, stream>>>(bufC, N, Wl2, bl2, Wr2, br2, xlb, bufB);
    k_fusedb<<<grdFused, 256, 0, stream>>>(row_off, csr_src, xlb, bufB, att2, b2, bufC, N);

    // ---- Layer 3: 128 -> 32 (H=1,C=32), bf16 xl ----
    k_linear3b<<<grdLin, 256, 0, stream>>>(bufC, N, Wl3, bl3, Wr3, br3, xlb, bufB);
    k_fused3<<<grdFused, 256, 0, stream>>>(row_off, csr_src, xlb, bufB, att3, b3, bufC, N);

    // ---- pooling ----
    k_pool_partial<<<256, 256, 0, stream>>>(bufC, batch, N, G, gsum, gmax);
    k_pool_final<<<G, 64, 0, stream>>>(gsum, gmax, batch, N, (float*)d_out);
}